// Round 10
// baseline (27.393 us; speedup 1.0000x reference)
//
#include <hip/hip_runtime.h>
#include <math.h>

#define NQ 10
#define QDEPTH 4
#define BLK 256
#define WPS 4            // waves (samples) per block

typedef float v2f __attribute__((ext_vector_type(2)));

__device__ __forceinline__ int   asi(float v) { return __builtin_bit_cast(int, v); }
__device__ __forceinline__ float asf(int v)   { return __builtin_bit_cast(float, v); }

// exact lane^D partner: D=1,2 quad_perm; D=8 row_ror:8 (xor8==rot8 in row16); D=4 ds_swizzle
template<int D>
__device__ __forceinline__ float exch(float v) {
    if constexpr (D == 1)
        return asf(__builtin_amdgcn_update_dpp(asi(v), asi(v), 0xB1, 0xF, 0xF, true));
    else if constexpr (D == 2)
        return asf(__builtin_amdgcn_update_dpp(asi(v), asi(v), 0x4E, 0xF, 0xF, true));
    else if constexpr (D == 8)
        return asf(__builtin_amdgcn_update_dpp(asi(v), asi(v), 0x128, 0xF, 0xF, true));
    else
        return asf(__builtin_amdgcn_ds_swizzle(asi(v), 0x101F));   // D==4
}

// v + v[lane^16] / v + v[lane^32]  (VALU permlane swaps; identity HW-verified r5)
__device__ __forceinline__ float plsum16(float v) {
    unsigned u = (unsigned)asi(v);
    auto r = __builtin_amdgcn_permlane16_swap(u, u, false, false);
    return asf((int)r[0]) + asf((int)r[1]);
}
__device__ __forceinline__ float plsum32(float v) {
    unsigned u = (unsigned)asi(v);
    auto r = __builtin_amdgcn_permlane32_swap(u, u, false, false);
    return asf((int)r[0]) + asf((int)r[1]);
}
// v * v[lane^16] / v * v[lane^32]
__device__ __forceinline__ float plmul16(float v) {
    unsigned u = (unsigned)asi(v);
    auto r = __builtin_amdgcn_permlane16_swap(u, u, false, false);
    return asf((int)r[0]) * asf((int)r[1]);
}
__device__ __forceinline__ float plmul32(float v) {
    unsigned u = (unsigned)asi(v);
    auto r = __builtin_amdgcn_permlane32_swap(u, u, false, false);
    return asf((int)r[0]) * asf((int)r[1]);
}

__device__ __forceinline__ float rlane(float v, int l) {
    return asf(__builtin_amdgcn_readlane(asi(v), l));
}

// branchless sincos for |h| <= ~3.5 (one Cody-Waite pi-reduction)
__device__ __forceinline__ void fast_sincos(float h, float* sp, float* cp) {
    float nf = __builtin_rintf(h * 0.31830987f);         // n = rint(h/pi)
    float r  = fmaf(nf, -3.14159274f, h);                // h - n*pi_hi
    r        = fmaf(nf,  8.7422777e-8f, r);              // - n*pi_lo
    int  sg  = (((int)nf) & 1) << 31;                    // (-1)^n
    float x2 = r * r;
    float q  = fmaf(x2, -2.5052108e-8f, 2.7557319e-6f);  // sin poly (Taylor deg 11)
    q = fmaf(x2, q, -1.9841270e-4f);
    q = fmaf(x2, q,  8.3333333e-3f);
    q = fmaf(x2, q, -0.16666667f);
    float s  = fmaf(r * x2, q, r);
    float c2 = fmaf(x2,  2.0876757e-9f, -2.7557319e-7f); // cos poly (Taylor deg 12)
    c2 = fmaf(x2, c2,  2.4801587e-5f);
    c2 = fmaf(x2, c2, -1.3888889e-3f);
    c2 = fmaf(x2, c2,  4.1666667e-2f);
    c2 = fmaf(x2, c2, -0.5f);
    float c  = fmaf(x2, c2, 1.0f);
    *sp = asf(asi(s) ^ sg);
    *cp = asf(asi(c) ^ sg);
}

// local qubit Q (0..3), shear: (a,b) -> (a - t*b, b + t*a)
template<int Q>
__device__ __forceinline__ void local_gate_t(v2f (&P)[16], float t) {
    const v2f tt = {t, t};
    #pragma unroll
    for (int pp = 0; pp < 8; ++pp) {
        const int i0 = ((pp >> Q) << (Q + 1)) | (pp & ((1 << Q) - 1));
        const int i1 = i0 | (1 << Q);
        v2f a = P[i0], b = P[i1];
        P[i0] = a - tt * b;
        P[i1] = b + tt * a;
    }
}

// cross qubit, exact-partner exchange (D=1,2,4,8): P' = P + tvv*partner
template<int D>
__device__ __forceinline__ void cross_gate_t(v2f (&P)[16], float tvv) {
    const v2f tt = {tvv, tvv};
    #pragma unroll
    for (int r = 0; r < 16; ++r) {
        v2f pp;
        pp.x = exch<D>(P[r].x);
        pp.y = exch<D>(P[r].y);
        P[r] = P[r] + tt * pp;
    }
}

// cross qubit via permlane sum S = v+partner: P' = (1-t)*P + t*S  (== P + t*partner)
template<int D>  // D = 16 or 32
__device__ __forceinline__ void cross_gate_pl(v2f (&P)[16], float tvv) {
    const v2f tt = {tvv, tvv};
    const float om = 1.0f - tvv;
    const v2f om2 = {om, om};
    #pragma unroll
    for (int r = 0; r < 16; ++r) {
        v2f S;
        if constexpr (D == 16) { S.x = plsum16(P[r].x); S.y = plsum16(P[r].y); }
        else                   { S.x = plsum32(P[r].x); S.y = plsum32(P[r].y); }
        P[r] = om2 * P[r] + tt * S;
    }
}

__global__ __launch_bounds__(BLK, 4) void hybrid_kernel(
    const float* __restrict__ x,      // (B,10)
    const float* __restrict__ Ws,     // (5,10,10)
    const float* __restrict__ bs,     // (5,10)
    const float* __restrict__ theta,  // (4,10)
    const float* __restrict__ Wf,     // (2,20)
    const float* __restrict__ bfin,   // (2,)
    float* __restrict__ out)          // (B,2)
{
    const int tid  = threadIdx.x;
    const int lane = tid & 63;
    const int wv   = tid >> 6;
    const int s    = blockIdx.x * WPS + wv;   // sample index

    // ---- trig via lanes: 0..39 theta gates, 40..49 this sample's x
    float ang = 0.0f;
    if (lane < QDEPTH * NQ)              ang = theta[lane];
    else if (lane < QDEPTH * NQ + NQ)    ang = x[s * NQ + (lane - QDEPTH * NQ)];
    float sv_, cv_;
    fast_sincos(0.5f * ang, &sv_, &cv_);
    const float tv_ = sv_ * __builtin_amdgcn_rcpf(cv_);  // tan(ang/2)

    // wave-uniform C = prod over 40 gates of cos(theta/2); C2 scales probs
    float cc = (lane < QDEPTH * NQ) ? cv_ : 1.0f;
    cc *= exch<1>(cc);
    cc *= exch<2>(cc);
    cc *= exch<4>(cc);
    cc *= exch<8>(cc);
    cc  = plmul16(cc);
    cc  = plmul32(cc);
    const float C2 = cc * cc;

    // ---- init, original coords: amp_k = (-i)^popc(k) * r_k ; P[loc] = (re, im)
    const int pl = __popc(lane);
    v2f P[16];
    {
        float cq[4], sq[4];
        #pragma unroll
        for (int q = 0; q < 4; ++q) {
            cq[q] = rlane(cv_, QDEPTH * NQ + q);
            sq[q] = rlane(sv_, QDEPTH * NQ + q);
        }
        float lf = 1.0f;
        #pragma unroll
        for (int b = 0; b < 6; ++b) {
            float cb = rlane(cv_, QDEPTH * NQ + 4 + b);
            float sb = rlane(sv_, QDEPTH * NQ + 4 + b);
            lf *= ((lane >> b) & 1) ? sb : cb;
        }
        float p01[4], p23[4];
        p01[0] = cq[0] * cq[1]; p01[1] = sq[0] * cq[1];
        p01[2] = cq[0] * sq[1]; p01[3] = sq[0] * sq[1];
        p23[0] = cq[2] * cq[3]; p23[1] = sq[2] * cq[3];
        p23[2] = cq[2] * sq[3]; p23[3] = sq[2] * sq[3];
        #pragma unroll
        for (int loc = 0; loc < 16; ++loc) {
            float r = lf * p01[loc & 3] * p23[loc >> 2];
            int pm = (pl + __popc(loc)) & 3;   // (-i)^pm
            P[loc].x = (pm == 0) ? r : ((pm == 2) ? -r : 0.0f);
            P[loc].y = (pm == 1) ? -r : ((pm == 3) ? r : 0.0f);
        }
    }

    // ---- per-lane masks
    int zmask[6];
    #pragma unroll
    for (int b = 0; b < 6; ++b)
        zmask[b] = ((lane >> b) & 1) << 31;     // sign-flip word when lane bit set

    // CZ sign values: par(k) = P1(loc) ^ (locbit3 & lanebit0) ^ P3(lane); +-1.0 floats
    const int p3  = __popc(lane & (lane >> 1)) & 1;
    const float sAf = asf(0x3F800000 ^ (p3 << 31));
    const float sBf = asf(0x3F800000 ^ ((p3 ^ (lane & 1)) << 31));
    const v2f sA2 = { sAf,  sAf}, sB2 = { sBf,  sBf};
    const v2f nA2 = {-sAf, -sAf}, nB2 = {-sBf, -sBf};

    // ---- circuit: 4 x (10 RY shears + CZ chain); global factor C2 applied at end
    for (int l = 0; l < QDEPTH; ++l) {
        local_gate_t<0>(P, rlane(tv_, l * NQ + 0));
        local_gate_t<1>(P, rlane(tv_, l * NQ + 1));
        local_gate_t<2>(P, rlane(tv_, l * NQ + 2));
        local_gate_t<3>(P, rlane(tv_, l * NQ + 3));
        {
            float tvv;
            tvv = asf(asi(-rlane(tv_, l * NQ + 4)) ^ zmask[0]);
            cross_gate_t<1>(P, tvv);
            tvv = asf(asi(-rlane(tv_, l * NQ + 5)) ^ zmask[1]);
            cross_gate_t<2>(P, tvv);
            tvv = asf(asi(-rlane(tv_, l * NQ + 6)) ^ zmask[2]);
            cross_gate_t<4>(P, tvv);
            tvv = asf(asi(-rlane(tv_, l * NQ + 7)) ^ zmask[3]);
            cross_gate_t<8>(P, tvv);
            tvv = asf(asi(-rlane(tv_, l * NQ + 8)) ^ zmask[4]);
            cross_gate_pl<16>(P, tvv);
            tvv = asf(asi(-rlane(tv_, l * NQ + 9)) ^ zmask[5]);
            cross_gate_pl<32>(P, tvv);
        }
        // CZ chain: multiply by +-1 (exact), packed
        #pragma unroll
        for (int loc = 0; loc < 16; ++loc) {
            const int C1 = __popc(loc & (loc >> 1)) & 1;
            const v2f m = (loc & 8) ? (C1 ? nB2 : sB2) : (C1 ? nA2 : sA2);
            P[loc] = P[loc] * m;
        }
    }

    // ---- probs (unscaled) + folded quantum->output contraction
    float pr[16], S = 0.0f;
    #pragma unroll
    for (int loc = 0; loc < 16; ++loc) {
        pr[loc] = fmaf(P[loc].x, P[loc].x, P[loc].y * P[loc].y);
        S += pr[loc];
    }
    float U0 = 0.0f, U1 = 0.0f, U2 = 0.0f, U3 = 0.0f;
    #pragma unroll
    for (int loc = 0; loc < 16; ++loc) {
        if (loc & 1) U0 += pr[loc];
        if (loc & 2) U1 += pr[loc];
        if (loc & 4) U2 += pr[loc];
        if (loc & 8) U3 += pr[loc];
    }
    const float w00 = Wf[19], w01 = Wf[18], w02 = Wf[17], w03 = Wf[16];
    const float w10 = Wf[39], w11 = Wf[38], w12 = Wf[37], w13 = Wf[36];
    float d0 = ((w00 + w01) + (w02 + w03)) * S;
    float d1 = ((w10 + w11) + (w12 + w13)) * S;
    d0 = fmaf(-2.0f * w00, U0, d0); d0 = fmaf(-2.0f * w01, U1, d0);
    d0 = fmaf(-2.0f * w02, U2, d0); d0 = fmaf(-2.0f * w03, U3, d0);
    d1 = fmaf(-2.0f * w10, U0, d1); d1 = fmaf(-2.0f * w11, U1, d1);
    d1 = fmaf(-2.0f * w12, U2, d1); d1 = fmaf(-2.0f * w13, U3, d1);
    float L0 = 0.0f, L1 = 0.0f;
    #pragma unroll
    for (int b = 0; b < 6; ++b) {      // q = 4+b -> Wf[15-b] / Wf[35-b]
        L0 += asf(asi(Wf[15 - b]) ^ zmask[b]);
        L1 += asf(asi(Wf[35 - b]) ^ zmask[b]);
    }
    float qp0 = fmaf(L0, S, d0);
    float qp1 = fmaf(L1, S, d1);
    // reduce the 2 partials across 64 lanes (DS only at d4)
    qp0 += exch<1>(qp0);  qp1 += exch<1>(qp1);
    qp0 += exch<2>(qp0);  qp1 += exch<2>(qp1);
    qp0 += exch<4>(qp0);  qp1 += exch<4>(qp1);
    qp0 += exch<8>(qp0);  qp1 += exch<8>(qp1);
    qp0  = plsum16(qp0);  qp1  = plsum16(qp1);
    qp0  = plsum32(qp0);  qp1  = plsum32(qp1);

    // ---- classical MLP: lane i (<10) owns row i; broadcasts via readlane
    const int row = (lane < NQ) ? lane : 0;
    float h = x[s * NQ + row];
    #pragma unroll
    for (int l = 0; l < QDEPTH; ++l) {
        float v = bs[l * NQ + row];
        #pragma unroll
        for (int j = 0; j < NQ; ++j)
            v = fmaf(Ws[(l * NQ + row) * NQ + j], rlane(h, j), v);
        h = fmaxf(v, 0.0f);
    }
    float cls = bs[QDEPTH * NQ + row];
    #pragma unroll
    for (int j = 0; j < NQ; ++j)
        cls = fmaf(Ws[(QDEPTH * NQ + row) * NQ + j], rlane(h, j), cls);

    // ---- final linear (C2 scales the quantum contribution)
    float o0 = fmaf(C2, qp0, bfin[0]);
    float o1 = fmaf(C2, qp1, bfin[1]);
    #pragma unroll
    for (int j = 0; j < NQ; ++j) {
        float cj = rlane(cls, j);
        o0 = fmaf(Wf[j],      cj, o0);
        o1 = fmaf(Wf[20 + j], cj, o1);
    }
    if (lane == 0) {
        float2 o; o.x = o0; o.y = o1;
        *reinterpret_cast<float2*>(&out[s * 2]) = o;
    }
}

extern "C" void kernel_launch(void* const* d_in, const int* in_sizes, int n_in,
                              void* d_out, int out_size, void* d_ws, size_t ws_size,
                              hipStream_t stream) {
    const float* x     = (const float*)d_in[0];   // (4096,10)
    const float* Ws    = (const float*)d_in[1];   // (5,10,10)
    const float* bs    = (const float*)d_in[2];   // (5,10)
    const float* theta = (const float*)d_in[3];   // (4,10)
    const float* Wf    = (const float*)d_in[4];   // (2,20)
    const float* bfin  = (const float*)d_in[5];   // (2,)
    float* out = (float*)d_out;

    const int B = in_sizes[0] / NQ;               // 4096
    hybrid_kernel<<<B / WPS, BLK, 0, stream>>>(x, Ws, bs, theta, Wf, bfin, out);
}

// Round 11
// 26.825 us; speedup vs baseline: 1.0212x; 1.0212x over previous
//
#include <hip/hip_runtime.h>
#include <math.h>

#define NQ 10
#define QDEPTH 4
#define BLK 256          // 4 waves = 2 samples (2 waves per sample)

typedef float v2f __attribute__((ext_vector_type(2)));

__device__ __forceinline__ int   asi(float v) { return __builtin_bit_cast(int, v); }
__device__ __forceinline__ float asf(int v)   { return __builtin_bit_cast(float, v); }

// exact lane^D partner exchange; D=1,2 DPP (VALU), D=4,8,16 ds_swizzle, D=32 ds_bpermute
template<int D>
__device__ __forceinline__ float exch(float v, int addr32) {
    if constexpr (D == 1)
        return asf(__builtin_amdgcn_update_dpp(asi(v), asi(v), 0xB1, 0xF, 0xF, true));
    else if constexpr (D == 2)
        return asf(__builtin_amdgcn_update_dpp(asi(v), asi(v), 0x4E, 0xF, 0xF, true));
    else if constexpr (D == 4)
        return asf(__builtin_amdgcn_ds_swizzle(asi(v), 0x101F));
    else if constexpr (D == 8)
        return asf(__builtin_amdgcn_ds_swizzle(asi(v), 0x201F));
    else if constexpr (D == 16)
        return asf(__builtin_amdgcn_ds_swizzle(asi(v), 0x401F));
    else
        return asf(__builtin_amdgcn_ds_bpermute(addr32, asi(v)));
}

__device__ __forceinline__ float rlane(float v, int l) {
    return asf(__builtin_amdgcn_readlane(asi(v), l));
}

// local qubit Q (0..2) on 8 locs, shear: (a,b) -> (a - t*b, b + t*a)
template<int Q>
__device__ __forceinline__ void local_gate_t(v2f (&P)[8], float t) {
    const v2f tt = {t, t};
    #pragma unroll
    for (int pp = 0; pp < 4; ++pp) {
        const int i0 = ((pp >> Q) << (Q + 1)) | (pp & ((1 << Q) - 1));
        const int i1 = i0 | (1 << Q);
        v2f a = P[i0], b = P[i1];
        P[i0] = a - tt * b;
        P[i1] = b + tt * a;
    }
}

// cross qubit at lane distance D, shear: P' = P + tvv*partner (tvv carries per-lane sign)
template<int D>
__device__ __forceinline__ void cross_gate_t(v2f (&P)[8], float tvv, int addr32) {
    const v2f tt = {tvv, tvv};
    #pragma unroll
    for (int r = 0; r < 8; ++r) {
        v2f pp;
        pp.x = exch<D>(P[r].x, addr32);
        pp.y = exch<D>(P[r].y, addr32);
        P[r] = P[r] + tt * pp;
    }
}

__global__ __launch_bounds__(BLK, 8) void hybrid_kernel(
    const float* __restrict__ x,      // (B,10)
    const float* __restrict__ Ws,     // (5,10,10)
    const float* __restrict__ bs,     // (5,10)
    const float* __restrict__ theta,  // (4,10)
    const float* __restrict__ Wf,     // (2,20)
    const float* __restrict__ bfin,   // (2,)
    float* __restrict__ out)          // (B,2)
{
    const int tid     = threadIdx.x;
    const int lane    = tid & 63;
    const int wv      = tid >> 6;
    const int pairbit = wv & 1;                  // qubit-9 bit of this wave
    const int s       = blockIdx.x * 2 + (wv >> 1);  // sample index

    __shared__ v2f   xch[4][8][64];              // inter-wave exchange (16 KB)
    __shared__ float qpart[4][2];                // per-wave output partials

    // ---- trig via lanes: 0..39 theta gates, 40..49 this sample's x
    float ang = 0.0f;
    if (lane < QDEPTH * NQ)              ang = theta[lane];
    else if (lane < QDEPTH * NQ + NQ)    ang = x[s * NQ + (lane - QDEPTH * NQ)];
    float sv_, cv_;
    sincosf(0.5f * ang, &sv_, &cv_);
    const float tv_ = sv_ / cv_;                 // tan(ang/2) (lanes 0..39 used)

    const int addr32 = (lane ^ 32) << 2;         // ds_bpermute byte address

    // wave-uniform C = prod over 40 gates of cos(theta/2); C2 scales probs
    float cc = (lane < QDEPTH * NQ) ? cv_ : 1.0f;
    cc *= exch<1>(cc, addr32);
    cc *= exch<2>(cc, addr32);
    cc *= exch<4>(cc, addr32);
    cc *= exch<8>(cc, addr32);
    cc *= exch<16>(cc, addr32);
    cc *= exch<32>(cc, addr32);
    const float C2 = cc * cc;

    // ---- init: k = pairbit<<9 | lane<<3 | loc ; amp_k = (-i)^popc(k) * r_k
    const int pl = __popc(lane) + pairbit;
    v2f P[8];
    {
        float c0 = rlane(cv_, 40), s0 = rlane(sv_, 40);
        float c1 = rlane(cv_, 41), s1 = rlane(sv_, 41);
        float c2 = rlane(cv_, 42), s2 = rlane(sv_, 42);
        float lf = 1.0f;
        #pragma unroll
        for (int b = 0; b < 6; ++b) {            // lane bit b = qubit 3+b
            float cb = rlane(cv_, 43 + b);
            float sb = rlane(sv_, 43 + b);
            lf *= ((lane >> b) & 1) ? sb : cb;
        }
        lf *= pairbit ? rlane(sv_, 49) : rlane(cv_, 49);  // qubit 9
        float p01[4];
        p01[0] = c0 * c1; p01[1] = s0 * c1;
        p01[2] = c0 * s1; p01[3] = s0 * s1;
        #pragma unroll
        for (int loc = 0; loc < 8; ++loc) {
            float r = lf * p01[loc & 3] * ((loc & 4) ? s2 : c2);
            int pm = (pl + __popc(loc)) & 3;     // (-i)^pm
            P[loc].x = (pm == 0) ? r : ((pm == 2) ? -r : 0.0f);
            P[loc].y = (pm == 1) ? -r : ((pm == 3) ? r : 0.0f);
        }
    }

    // ---- per-lane masks (lane bit b = qubit 3+b)
    int zmask[6];
    #pragma unroll
    for (int b = 0; b < 6; ++b)
        zmask[b] = ((lane >> b) & 1) << 31;

    // CZ sign words: par(k) = P1(loc) ^ (locbit2 & lanebit0) ^ P3(lane) ^ (lanebit5 & pairbit)
    // P3(lane): qubit pairs (3,4)..(7,8) = lane bit pairs (0,1)..(4,5)
    const int p3   = __popc(lane & (lane >> 1)) & 1;
    const int base = (p3 ^ (((lane >> 5) & 1) & pairbit)) << 31;
    const int w00 = base;                        // locbit2=0, P1(loc)=0
    const int w01 = base ^ 0x80000000;           // locbit2=0, P1(loc)=1
    const int wB0 = base ^ ((lane & 1) << 31);   // locbit2=1, P1(loc)=0
    const int wB1 = wB0 ^ 0x80000000;            // locbit2=1, P1(loc)=1

    // ---- circuit: 4 x (10 RY shears + CZ chain); global factor C2 applied at end
    for (int l = 0; l < QDEPTH; ++l) {
        local_gate_t<0>(P, rlane(tv_, l * NQ + 0));
        local_gate_t<1>(P, rlane(tv_, l * NQ + 1));
        local_gate_t<2>(P, rlane(tv_, l * NQ + 2));
        {
            float tvv;
            tvv = asf(asi(-rlane(tv_, l * NQ + 3)) ^ zmask[0]);
            cross_gate_t<1>(P, tvv, addr32);
            tvv = asf(asi(-rlane(tv_, l * NQ + 4)) ^ zmask[1]);
            cross_gate_t<2>(P, tvv, addr32);
            tvv = asf(asi(-rlane(tv_, l * NQ + 5)) ^ zmask[2]);
            cross_gate_t<4>(P, tvv, addr32);
            tvv = asf(asi(-rlane(tv_, l * NQ + 6)) ^ zmask[3]);
            cross_gate_t<8>(P, tvv, addr32);
            tvv = asf(asi(-rlane(tv_, l * NQ + 7)) ^ zmask[4]);
            cross_gate_t<16>(P, tvv, addr32);
            tvv = asf(asi(-rlane(tv_, l * NQ + 8)) ^ zmask[5]);
            cross_gate_t<32>(P, tvv, addr32);
        }
        // qubit 9: inter-wave butterfly via LDS
        {
            const float t9  = rlane(tv_, l * NQ + 9);
            const float tv9 = asf(asi(-t9) ^ (pairbit << 31));
            const v2f   t92 = {tv9, tv9};
            #pragma unroll
            for (int r = 0; r < 8; ++r)
                xch[wv][r][lane] = P[r];
            __syncthreads();
            v2f Q[8];
            #pragma unroll
            for (int r = 0; r < 8; ++r)
                Q[r] = xch[wv ^ 1][r][lane];
            #pragma unroll
            for (int r = 0; r < 8; ++r)
                P[r] = P[r] + t92 * Q[r];
            __syncthreads();
        }
        // CZ chain: sign-bit XOR (per-loc compile-time select)
        #pragma unroll
        for (int loc = 0; loc < 8; ++loc) {
            const int m = (loc & 4) ? ((loc == 6) ? wB1 : wB0)
                                    : ((loc == 3) ? w01 : w00);
            P[loc].x = asf(asi(P[loc].x) ^ m);
            P[loc].y = asf(asi(P[loc].y) ^ m);
        }
    }

    // ---- probs (unscaled) + folded quantum->output contraction
    // loc bits = qubits 0,1,2 ; lane bits = qubits 3..8 ; pairbit = qubit 9
    float pr[8], S = 0.0f;
    #pragma unroll
    for (int loc = 0; loc < 8; ++loc) {
        pr[loc] = fmaf(P[loc].x, P[loc].x, P[loc].y * P[loc].y);
        S += pr[loc];
    }
    float U0 = 0.0f, U1 = 0.0f, U2 = 0.0f;
    #pragma unroll
    for (int loc = 0; loc < 8; ++loc) {
        if (loc & 1) U0 += pr[loc];
        if (loc & 2) U1 += pr[loc];
        if (loc & 4) U2 += pr[loc];
    }
    const float a00 = Wf[19], a01 = Wf[18], a02 = Wf[17];   // out0: q0,q1,q2
    const float a10 = Wf[39], a11 = Wf[38], a12 = Wf[37];   // out1
    float d0 = ((a00 + a01) + a02) * S;
    float d1 = ((a10 + a11) + a12) * S;
    d0 = fmaf(-2.0f * a00, U0, d0); d0 = fmaf(-2.0f * a01, U1, d0);
    d0 = fmaf(-2.0f * a02, U2, d0);
    d1 = fmaf(-2.0f * a10, U0, d1); d1 = fmaf(-2.0f * a11, U1, d1);
    d1 = fmaf(-2.0f * a12, U2, d1);
    float L0 = asf(asi(Wf[10]) ^ (pairbit << 31));          // qubit 9
    float L1 = asf(asi(Wf[30]) ^ (pairbit << 31));
    #pragma unroll
    for (int b = 0; b < 6; ++b) {      // qubit 3+b -> Wf[16-b] / Wf[36-b]
        L0 += asf(asi(Wf[16 - b]) ^ zmask[b]);
        L1 += asf(asi(Wf[36 - b]) ^ zmask[b]);
    }
    float qp0 = fmaf(L0, S, d0);
    float qp1 = fmaf(L1, S, d1);
    // reduce across 64 lanes
    qp0 += exch<1>(qp0, addr32);  qp1 += exch<1>(qp1, addr32);
    qp0 += exch<2>(qp0, addr32);  qp1 += exch<2>(qp1, addr32);
    qp0 += exch<4>(qp0, addr32);  qp1 += exch<4>(qp1, addr32);
    qp0 += exch<8>(qp0, addr32);  qp1 += exch<8>(qp1, addr32);
    qp0 += exch<16>(qp0, addr32); qp1 += exch<16>(qp1, addr32);
    qp0 += exch<32>(qp0, addr32); qp1 += exch<32>(qp1, addr32);

    if (lane == 0) { qpart[wv][0] = qp0; qpart[wv][1] = qp1; }
    __syncthreads();                 // last barrier; all 4 waves reach it

    if (pairbit) return;             // wave 1 of each pair is done

    // ---- wave 0: combine pair, classical MLP, final linear, store
    const float qs0 = qp0 + qpart[wv ^ 1][0];
    const float qs1 = qp1 + qpart[wv ^ 1][1];

    const int row = (lane < NQ) ? lane : 0;
    float h = x[s * NQ + row];
    #pragma unroll
    for (int l = 0; l < QDEPTH; ++l) {
        float v = bs[l * NQ + row];
        #pragma unroll
        for (int j = 0; j < NQ; ++j)
            v = fmaf(Ws[(l * NQ + row) * NQ + j], rlane(h, j), v);
        h = fmaxf(v, 0.0f);
    }
    float cls = bs[QDEPTH * NQ + row];
    #pragma unroll
    for (int j = 0; j < NQ; ++j)
        cls = fmaf(Ws[(QDEPTH * NQ + row) * NQ + j], rlane(h, j), cls);

    float o0 = fmaf(C2, qs0, bfin[0]);
    float o1 = fmaf(C2, qs1, bfin[1]);
    #pragma unroll
    for (int j = 0; j < NQ; ++j) {
        float cj = rlane(cls, j);
        o0 = fmaf(Wf[j],      cj, o0);
        o1 = fmaf(Wf[20 + j], cj, o1);
    }
    if (lane == 0) {
        float2 o; o.x = o0; o.y = o1;
        *reinterpret_cast<float2*>(&out[s * 2]) = o;
    }
}

extern "C" void kernel_launch(void* const* d_in, const int* in_sizes, int n_in,
                              void* d_out, int out_size, void* d_ws, size_t ws_size,
                              hipStream_t stream) {
    const float* x     = (const float*)d_in[0];   // (4096,10)
    const float* Ws    = (const float*)d_in[1];   // (5,10,10)
    const float* bs    = (const float*)d_in[2];   // (5,10)
    const float* theta = (const float*)d_in[3];   // (4,10)
    const float* Wf    = (const float*)d_in[4];   // (2,20)
    const float* bfin  = (const float*)d_in[5];   // (2,)
    float* out = (float*)d_out;

    const int B = in_sizes[0] / NQ;               // 4096
    hybrid_kernel<<<B / 2, BLK, 0, stream>>>(x, Ws, bs, theta, Wf, bfin, out);
}

// Round 12
// 24.909 us; speedup vs baseline: 1.0997x; 1.0769x over previous
//
#include <hip/hip_runtime.h>
#include <math.h>

#define NQ 10
#define QDEPTH 4
#define BLK 512
#define WPS 8            // waves (samples) per block

typedef float v2f __attribute__((ext_vector_type(2)));

__device__ __forceinline__ int   asi(float v) { return __builtin_bit_cast(int, v); }
__device__ __forceinline__ float asf(int v)   { return __builtin_bit_cast(float, v); }

// exact lane^D partner exchange; D=1,2 DPP (VALU), D=4,8,16 ds_swizzle, D=32 ds_bpermute
template<int D>
__device__ __forceinline__ float exch(float v, int addr32) {
    if constexpr (D == 1)
        return asf(__builtin_amdgcn_update_dpp(asi(v), asi(v), 0xB1, 0xF, 0xF, true));
    else if constexpr (D == 2)
        return asf(__builtin_amdgcn_update_dpp(asi(v), asi(v), 0x4E, 0xF, 0xF, true));
    else if constexpr (D == 4)
        return asf(__builtin_amdgcn_ds_swizzle(asi(v), 0x101F));
    else if constexpr (D == 8)
        return asf(__builtin_amdgcn_ds_swizzle(asi(v), 0x201F));
    else if constexpr (D == 16)
        return asf(__builtin_amdgcn_ds_swizzle(asi(v), 0x401F));
    else
        return asf(__builtin_amdgcn_ds_bpermute(addr32, asi(v)));
}

__device__ __forceinline__ float rlane(float v, int l) {
    return asf(__builtin_amdgcn_readlane(asi(v), l));
}

// branchless sincos for |h| <= ~3.5 (one Cody-Waite pi-reduction) — validated R10
__device__ __forceinline__ void fast_sincos(float h, float* sp, float* cp) {
    float nf = __builtin_rintf(h * 0.31830987f);         // n = rint(h/pi)
    float r  = fmaf(nf, -3.14159274f, h);                // h - n*pi_hi
    r        = fmaf(nf,  8.7422777e-8f, r);              // - n*pi_lo
    int  sg  = (((int)nf) & 1) << 31;                    // (-1)^n
    float x2 = r * r;
    float q  = fmaf(x2, -2.5052108e-8f, 2.7557319e-6f);  // sin poly
    q = fmaf(x2, q, -1.9841270e-4f);
    q = fmaf(x2, q,  8.3333333e-3f);
    q = fmaf(x2, q, -0.16666667f);
    float s  = fmaf(r * x2, q, r);
    float c2 = fmaf(x2,  2.0876757e-9f, -2.7557319e-7f); // cos poly
    c2 = fmaf(x2, c2,  2.4801587e-5f);
    c2 = fmaf(x2, c2, -1.3888889e-3f);
    c2 = fmaf(x2, c2,  4.1666667e-2f);
    c2 = fmaf(x2, c2, -0.5f);
    float c  = fmaf(x2, c2, 1.0f);
    *sp = asf(asi(s) ^ sg);
    *cp = asf(asi(c) ^ sg);
}

// local qubit Q (0..3), shear: (a,b) -> (a - t*b, b + t*a)
template<int Q>
__device__ __forceinline__ void local_gate_t(v2f (&P)[16], float t) {
    const v2f tt = {t, t};
    #pragma unroll
    for (int pp = 0; pp < 8; ++pp) {
        const int i0 = ((pp >> Q) << (Q + 1)) | (pp & ((1 << Q) - 1));
        const int i1 = i0 | (1 << Q);
        v2f a = P[i0], b = P[i1];
        P[i0] = a - tt * b;
        P[i1] = b + tt * a;
    }
}

// cross qubit at lane distance D, shear: P' = P + tvv*partner (tvv carries per-lane sign)
template<int D>
__device__ __forceinline__ void cross_gate_t(v2f (&P)[16], float tvv, int addr32) {
    const v2f tt = {tvv, tvv};
    #pragma unroll
    for (int r = 0; r < 16; ++r) {
        v2f pp;
        pp.x = exch<D>(P[r].x, addr32);
        pp.y = exch<D>(P[r].y, addr32);
        P[r] = P[r] + tt * pp;
    }
}

__global__ __launch_bounds__(BLK, 4) void hybrid_kernel(
    const float* __restrict__ x,      // (B,10)
    const float* __restrict__ Ws,     // (5,10,10)
    const float* __restrict__ bs,     // (5,10)
    const float* __restrict__ theta,  // (4,10)
    const float* __restrict__ Wf,     // (2,20)
    const float* __restrict__ bfin,   // (2,)
    float* __restrict__ out)          // (B,2)
{
    const int tid  = threadIdx.x;
    const int lane = tid & 63;
    const int wv   = tid >> 6;
    const int s    = blockIdx.x * WPS + wv;   // sample index

    // ---- trig via lanes: 0..39 theta gates, 40..49 this sample's x
    float ang = 0.0f;
    if (lane < QDEPTH * NQ)              ang = theta[lane];
    else if (lane < QDEPTH * NQ + NQ)    ang = x[s * NQ + (lane - QDEPTH * NQ)];
    float sv_, cv_;
    fast_sincos(0.5f * ang, &sv_, &cv_);
    const float tv_ = sv_ / cv_;              // tan(ang/2) (lanes 0..39 used)

    const int addr32 = (lane ^ 32) << 2;      // ds_bpermute byte address

    // wave-uniform C = prod over the 40 gates of cos(theta/2); C2 scales probs
    float cc = (lane < QDEPTH * NQ) ? cv_ : 1.0f;
    cc *= exch<1>(cc, addr32);
    cc *= exch<2>(cc, addr32);
    cc *= exch<4>(cc, addr32);
    cc *= exch<8>(cc, addr32);
    cc *= exch<16>(cc, addr32);
    cc *= exch<32>(cc, addr32);
    const float C2 = cc * cc;

    // ---- init, original coords: amp_k = (-i)^popc(k) * r_k ; P[loc] = (re, im)
    const int pl = __popc(lane);
    v2f P[16];
    {
        float cq[4], sq[4];
        #pragma unroll
        for (int q = 0; q < 4; ++q) {
            cq[q] = rlane(cv_, QDEPTH * NQ + q);
            sq[q] = rlane(sv_, QDEPTH * NQ + q);
        }
        float lf = 1.0f;
        #pragma unroll
        for (int b = 0; b < 6; ++b) {
            float cb = rlane(cv_, QDEPTH * NQ + 4 + b);
            float sb = rlane(sv_, QDEPTH * NQ + 4 + b);
            lf *= ((lane >> b) & 1) ? sb : cb;
        }
        float p01[4], p23[4];
        p01[0] = cq[0] * cq[1]; p01[1] = sq[0] * cq[1];
        p01[2] = cq[0] * sq[1]; p01[3] = sq[0] * sq[1];
        p23[0] = cq[2] * cq[3]; p23[1] = sq[2] * cq[3];
        p23[2] = cq[2] * sq[3]; p23[3] = sq[2] * sq[3];
        #pragma unroll
        for (int loc = 0; loc < 16; ++loc) {
            float r = lf * p01[loc & 3] * p23[loc >> 2];
            int pm = (pl + __popc(loc)) & 3;   // (-i)^pm
            P[loc].x = (pm == 0) ? r : ((pm == 2) ? -r : 0.0f);
            P[loc].y = (pm == 1) ? -r : ((pm == 3) ? r : 0.0f);
        }
    }

    // ---- per-lane masks
    int zmask[6];
    #pragma unroll
    for (int b = 0; b < 6; ++b)
        zmask[b] = ((lane >> b) & 1) << 31;     // sign-flip word when lane bit set

    // CZ sign words: par(k) = P1(loc) ^ (locbit3 & lanebit0) ^ P3(lane)
    const int p3  = __popc(lane & (lane >> 1)) & 1;
    const int sAw = p3 << 31;
    const int sBw = (p3 ^ (lane & 1)) << 31;
    const int sAn = sAw ^ 0x80000000;
    const int sBn = sBw ^ 0x80000000;

    // ---- circuit: 4 x (10 RY shears + CZ chain); global factor C2 applied at end
    for (int l = 0; l < QDEPTH; ++l) {
        local_gate_t<0>(P, rlane(tv_, l * NQ + 0));
        local_gate_t<1>(P, rlane(tv_, l * NQ + 1));
        local_gate_t<2>(P, rlane(tv_, l * NQ + 2));
        local_gate_t<3>(P, rlane(tv_, l * NQ + 3));
        {
            float tvv;
            tvv = asf(asi(-rlane(tv_, l * NQ + 4)) ^ zmask[0]);
            cross_gate_t<1>(P, tvv, addr32);
            tvv = asf(asi(-rlane(tv_, l * NQ + 5)) ^ zmask[1]);
            cross_gate_t<2>(P, tvv, addr32);
            tvv = asf(asi(-rlane(tv_, l * NQ + 6)) ^ zmask[2]);
            cross_gate_t<4>(P, tvv, addr32);
            tvv = asf(asi(-rlane(tv_, l * NQ + 7)) ^ zmask[3]);
            cross_gate_t<8>(P, tvv, addr32);
            tvv = asf(asi(-rlane(tv_, l * NQ + 8)) ^ zmask[4]);
            cross_gate_t<16>(P, tvv, addr32);
            tvv = asf(asi(-rlane(tv_, l * NQ + 9)) ^ zmask[5]);
            cross_gate_t<32>(P, tvv, addr32);
        }
        // CZ chain: sign-bit XOR
        #pragma unroll
        for (int loc = 0; loc < 16; ++loc) {
            const int C1 = __popc(loc & (loc >> 1)) & 1;
            const int m  = (loc & 8) ? (C1 ? sBn : sBw) : (C1 ? sAn : sAw);
            P[loc].x = asf(asi(P[loc].x) ^ m);
            P[loc].y = asf(asi(P[loc].y) ^ m);
        }
    }

    // ---- probs (unscaled) + folded quantum->output contraction
    float pr[16], S = 0.0f;
    #pragma unroll
    for (int loc = 0; loc < 16; ++loc) {
        pr[loc] = fmaf(P[loc].x, P[loc].x, P[loc].y * P[loc].y);
        S += pr[loc];
    }
    float U0 = 0.0f, U1 = 0.0f, U2 = 0.0f, U3 = 0.0f;
    #pragma unroll
    for (int loc = 0; loc < 16; ++loc) {
        if (loc & 1) U0 += pr[loc];
        if (loc & 2) U1 += pr[loc];
        if (loc & 4) U2 += pr[loc];
        if (loc & 8) U3 += pr[loc];
    }
    const float w00 = Wf[19], w01 = Wf[18], w02 = Wf[17], w03 = Wf[16];
    const float w10 = Wf[39], w11 = Wf[38], w12 = Wf[37], w13 = Wf[36];
    float d0 = ((w00 + w01) + (w02 + w03)) * S;
    float d1 = ((w10 + w11) + (w12 + w13)) * S;
    d0 = fmaf(-2.0f * w00, U0, d0); d0 = fmaf(-2.0f * w01, U1, d0);
    d0 = fmaf(-2.0f * w02, U2, d0); d0 = fmaf(-2.0f * w03, U3, d0);
    d1 = fmaf(-2.0f * w10, U0, d1); d1 = fmaf(-2.0f * w11, U1, d1);
    d1 = fmaf(-2.0f * w12, U2, d1); d1 = fmaf(-2.0f * w13, U3, d1);
    float L0 = 0.0f, L1 = 0.0f;
    #pragma unroll
    for (int b = 0; b < 6; ++b) {      // q = 4+b -> Wf[15-b] / Wf[35-b]
        L0 += asf(asi(Wf[15 - b]) ^ zmask[b]);
        L1 += asf(asi(Wf[35 - b]) ^ zmask[b]);
    }
    float qp0 = fmaf(L0, S, d0);
    float qp1 = fmaf(L1, S, d1);
    // reduce the 2 partials across 64 lanes
    qp0 += exch<1>(qp0, addr32);  qp1 += exch<1>(qp1, addr32);
    qp0 += exch<2>(qp0, addr32);  qp1 += exch<2>(qp1, addr32);
    qp0 += exch<4>(qp0, addr32);  qp1 += exch<4>(qp1, addr32);
    qp0 += exch<8>(qp0, addr32);  qp1 += exch<8>(qp1, addr32);
    qp0 += exch<16>(qp0, addr32); qp1 += exch<16>(qp1, addr32);
    qp0 += exch<32>(qp0, addr32); qp1 += exch<32>(qp1, addr32);

    // ---- classical MLP: lane i (<10) owns row i; broadcasts via readlane
    const int row = (lane < NQ) ? lane : 0;
    float h = x[s * NQ + row];
    #pragma unroll
    for (int l = 0; l < QDEPTH; ++l) {
        float v = bs[l * NQ + row];
        #pragma unroll
        for (int j = 0; j < NQ; ++j)
            v = fmaf(Ws[(l * NQ + row) * NQ + j], rlane(h, j), v);
        h = fmaxf(v, 0.0f);
    }
    float cls = bs[QDEPTH * NQ + row];
    #pragma unroll
    for (int j = 0; j < NQ; ++j)
        cls = fmaf(Ws[(QDEPTH * NQ + row) * NQ + j], rlane(h, j), cls);

    // ---- final linear (C2 scales the quantum contribution)
    float o0 = fmaf(C2, qp0, bfin[0]);
    float o1 = fmaf(C2, qp1, bfin[1]);
    #pragma unroll
    for (int j = 0; j < NQ; ++j) {
        float cj = rlane(cls, j);
        o0 = fmaf(Wf[j],      cj, o0);
        o1 = fmaf(Wf[20 + j], cj, o1);
    }
    if (lane == 0) {
        float2 o; o.x = o0; o.y = o1;
        *reinterpret_cast<float2*>(&out[s * 2]) = o;
    }
}

extern "C" void kernel_launch(void* const* d_in, const int* in_sizes, int n_in,
                              void* d_out, int out_size, void* d_ws, size_t ws_size,
                              hipStream_t stream) {
    const float* x     = (const float*)d_in[0];   // (4096,10)
    const float* Ws    = (const float*)d_in[1];   // (5,10,10)
    const float* bs    = (const float*)d_in[2];   // (5,10)
    const float* theta = (const float*)d_in[3];   // (4,10)
    const float* Wf    = (const float*)d_in[4];   // (2,20)
    const float* bfin  = (const float*)d_in[5];   // (2,)
    float* out = (float*)d_out;

    const int B = in_sizes[0] / NQ;               // 4096
    hybrid_kernel<<<B / WPS, BLK, 0, stream>>>(x, Ws, bs, theta, Wf, bfin, out);
}